// Round 6
// baseline (476.967 us; speedup 1.0000x reference)
//
#include <hip/hip_runtime.h>
#include <hip/hip_bf16.h>

#define NB 4
#define NN 256
#define DD 128
#define HH 256

typedef float f32x4 __attribute__((ext_vector_type(4)));
typedef short s16x8 __attribute__((ext_vector_type(8)));

static __device__ __forceinline__ unsigned short f2bf(float x) {
  unsigned int u = __builtin_bit_cast(unsigned int, x);
  u += 0x7fffu + ((u >> 16) & 1u);   // RNE
  return (unsigned short)(u >> 16);
}

static __device__ __forceinline__ float bf2f(unsigned short h) {
  unsigned int u = ((unsigned int)h) << 16;
  return __builtin_bit_cast(float, u);
}

// XOR-swizzle on short-offset within a row; 16B granules, bits 3..5
#define SWZ(off, row) ((off) ^ (((row) & 7) << 3))

// ---------------------------------------------------------------------------
// Kernel 1: agg partials, contiguous-stream layout.
// Block = (b, jc, ic): streams e[b, i, jc*8..+7, :] contiguously per i.
// Thread t: jl = t>>5 (8 j's), dq = (t&31)*4.  Accumulates in one f32x4.
// part[ic][b*256+j][d] = sum_{i in chunk} adj[b,i,j]*mi*(x[b,i,d]+e[b,i,j,d]*mj)
// ---------------------------------------------------------------------------
template<int NCH>
__global__ __launch_bounds__(256) void k_aggA(
    const float* __restrict__ emb_node, const float* __restrict__ emb_edge,
    const float* __restrict__ adj, const float* __restrict__ mask,
    float* __restrict__ part) {
  constexpr int IPC = NN / NCH;
  const int bid = blockIdx.x;
  const int b = bid / (32 * NCH);
  const int rem = bid % (32 * NCH);
  const int jc = rem / NCH, ic = rem % NCH;
  const int t = threadIdx.x;
  const int jl = t >> 5, dq = (t & 31) * 4;
  const int j = jc * 8 + jl;
  const int bj = b * NN + j;
  const float mj = mask[bj];
  f32x4 acc = {0.f, 0.f, 0.f, 0.f};
#pragma unroll 4
  for (int ii = 0; ii < IPC; ++ii) {
    const int bi = b * NN + ic * IPC + ii;
    const float am = adj[(size_t)bi * NN + j] * mask[bi];
    const float4 ev = *(const float4*)(emb_edge + ((size_t)bi * NN + j) * DD + dq);
    const float4 xv = *(const float4*)(emb_node + (size_t)bi * DD + dq);
    acc[0] += am * (xv.x + mj * ev.x);
    acc[1] += am * (xv.y + mj * ev.y);
    acc[2] += am * (xv.z + mj * ev.z);
    acc[3] += am * (xv.w + mj * ev.w);
  }
  *(f32x4*)(part + ((size_t)ic * (NB * NN) + bj) * DD + dq) = acc;
}

// ---------------------------------------------------------------------------
// Kernel 2: reduce partials -> x_new_pre; node MLP; out_x = LN(x + x_mlp);
//           Pi = x_mlp@W1a; Pj = x_mlp@W1b + eb1.  4 rows/block, 256 blocks.
// ---------------------------------------------------------------------------
__global__ __launch_bounds__(256) void k_node(
    const float* __restrict__ emb_node, const float* __restrict__ mask,
    const float* __restrict__ part, int nch,
    const float* __restrict__ nW1, const float* __restrict__ nb1,
    const float* __restrict__ nW2, const float* __restrict__ nb2,
    const float* __restrict__ eW1, const float* __restrict__ eb1,
    const float* __restrict__ gX, const float* __restrict__ bX,
    float* __restrict__ out_x, float* __restrict__ Pi, float* __restrict__ Pj) {
  __shared__ float xr[4][DD];
  __shared__ float hb[4][HH];
  __shared__ float xmb[4][DD];
  const int t = threadIdx.x;
  const int row0 = blockIdx.x * 4;
  for (int k = t; k < 4 * DD; k += 256) {
    const int row = row0 + (k >> 7), d = k & 127;
    float v = emb_node[(size_t)row * DD + d] * mask[row];
    for (int cc = 0; cc < nch; ++cc) v += part[((size_t)cc * (NB * NN) + row) * DD + d];
    xr[k >> 7][d] = v;
  }
  __syncthreads();
  { // layer 1
    float a0 = nb1[t], a1 = a0, a2 = a0, a3 = a0;
#pragma unroll 4
    for (int d = 0; d < DD; ++d) {
      float w = nW1[d * HH + t];
      a0 = fmaf(xr[0][d], w, a0); a1 = fmaf(xr[1][d], w, a1);
      a2 = fmaf(xr[2][d], w, a2); a3 = fmaf(xr[3][d], w, a3);
    }
    hb[0][t] = fmaxf(a0, 0.f); hb[1][t] = fmaxf(a1, 0.f);
    hb[2][t] = fmaxf(a2, 0.f); hb[3][t] = fmaxf(a3, 0.f);
  }
  __syncthreads();
  { // layer 2
    const int d = t & 127, rp = (t >> 7) * 2;
    float a0 = nb2[d], a1 = a0;
#pragma unroll 4
    for (int h = 0; h < HH; ++h) {
      float w = nW2[h * DD + d];
      a0 = fmaf(hb[rp][h], w, a0);
      a1 = fmaf(hb[rp + 1][h], w, a1);
    }
    xmb[rp][d] = a0; xmb[rp + 1][d] = a1;
  }
  __syncthreads();
  { // out_x = LN(x + x_mlp)
    const int w = t >> 6, l = t & 63;
    const int grow = row0 + w;
    const float m = mask[grow];
    const int d0 = 2 * l;
    float v0 = emb_node[(size_t)grow * DD + d0] * m + xmb[w][d0];
    float v1 = emb_node[(size_t)grow * DD + d0 + 1] * m + xmb[w][d0 + 1];
    float s = v0 + v1, s2 = v0 * v0 + v1 * v1;
#pragma unroll
    for (int off = 1; off < 64; off <<= 1) { s += __shfl_xor(s, off); s2 += __shfl_xor(s2, off); }
    const float mu = s * (1.f / 128.f);
    const float var = s2 * (1.f / 128.f) - mu * mu;
    const float rstd = 1.f / sqrtf(var + 1e-5f);
    out_x[(size_t)grow * DD + d0] = (v0 - mu) * rstd * gX[d0] + bX[d0];
    out_x[(size_t)grow * DD + d0 + 1] = (v1 - mu) * rstd * gX[d0 + 1] + bX[d0 + 1];
  }
  { // Pi / Pj
    float pi0 = 0.f, pi1 = 0.f, pi2 = 0.f, pi3 = 0.f;
    const float e1 = eb1[t];
    float pj0 = e1, pj1 = e1, pj2 = e1, pj3 = e1;
#pragma unroll 2
    for (int d = 0; d < DD; ++d) {
      const float wa = eW1[d * HH + t];
      const float wb = eW1[(DD + d) * HH + t];
      const float x0 = xmb[0][d], x1 = xmb[1][d], x2 = xmb[2][d], x3 = xmb[3][d];
      pi0 = fmaf(x0, wa, pi0); pi1 = fmaf(x1, wa, pi1);
      pi2 = fmaf(x2, wa, pi2); pi3 = fmaf(x3, wa, pi3);
      pj0 = fmaf(x0, wb, pj0); pj1 = fmaf(x1, wb, pj1);
      pj2 = fmaf(x2, wb, pj2); pj3 = fmaf(x3, wb, pj3);
    }
    Pi[(size_t)(row0 + 0) * HH + t] = pi0; Pi[(size_t)(row0 + 1) * HH + t] = pi1;
    Pi[(size_t)(row0 + 2) * HH + t] = pi2; Pi[(size_t)(row0 + 3) * HH + t] = pi3;
    Pj[(size_t)(row0 + 0) * HH + t] = pj0; Pj[(size_t)(row0 + 1) * HH + t] = pj1;
    Pj[(size_t)(row0 + 2) * HH + t] = pj2; Pj[(size_t)(row0 + 3) * HH + t] = pj3;
  }
}

// ---------------------------------------------------------------------------
// Kernel 3: edge MLP + residual LN.  GEMM1 swapped (S[h][m]), GEMM2 swapped
// (D[dout][m]) so lane's D-column = its own activation row m.
// 256 blocks x 1024 threads.  launch_bounds(1024, 1): under EITHER semantics
// of the 2nd arg (min blocks/CU or min waves/EU) this allows >=128 VGPR —
// (1024,4) was interpreted as 4 blocks/CU -> 8 waves/SIMD -> 64-VGPR cap ->
// scratch spill (seen as +105 MB FETCH / +134 MB WRITE in r3/r4 profiles).
// ---------------------------------------------------------------------------
__global__ __launch_bounds__(1024, 1) void k_edge(
    const float* __restrict__ emb_edge, const float* __restrict__ mask,
    const float* __restrict__ Pi, const float* __restrict__ Pj,
    const float* __restrict__ eW1, const float* __restrict__ eW2,
    const float* __restrict__ eb2, const float* __restrict__ gE,
    const float* __restrict__ bE, float* __restrict__ out_e) {
  __shared__ __align__(16) unsigned char smem[133632];
  short* w1t = (short*)smem;                 // [h=256][128 shorts]  = 65536 B
  short* w2t = (short*)(smem + 65536);       // [dout=128][256 shorts] = 65536 B
  float* Pis  = (float*)(smem + 131072);     // 256 f32
  float* eb2s = (float*)(smem + 132096);     // 128 f32
  float* gEs  = (float*)(smem + 132608);     // 128 f32
  float* bEs  = (float*)(smem + 133120);     // 128 f32

  const int t = threadIdx.x;
  // Stage W1c^T: slot p = kt*32 + 8g + s holds k = kt*32 + (s<4 ? 4g+s : 16+4g+s-4)
  for (int idx = t; idx < DD * HH; idx += 1024) {
    const int h = idx & 255, p = idx >> 8;          // p in [0,128)
    const int kt = p >> 5, r = p & 31, g = r >> 3, s = r & 7;
    const int k = kt * 32 + (s < 4 ? 4 * g + s : 16 + 4 * g + (s - 4));
    w1t[h * 128 + SWZ(p, h)] = (short)f2bf(eW1[(2 * DD + k) * HH + h]);
  }
  // Stage W2^T with same slot convention over h
  for (int idx = t; idx < DD * HH; idx += 1024) {
    const int dout = idx & 127, p = idx >> 7;       // p in [0,256)
    const int kt = p >> 5, r = p & 31, g = r >> 3, s = r & 7;
    const int h = kt * 32 + (s < 4 ? 4 * g + s : 16 + 4 * g + (s - 4));
    w2t[dout * 256 + SWZ(p, dout)] = (short)f2bf(eW2[h * DD + dout]);
  }
  if (t < 128) { eb2s[t] = eb2[t]; gEs[t] = gE[t]; bEs[t] = bE[t]; }
  __syncthreads();

  const int wv = t >> 6, lane = t & 63;
  const int lr = lane & 15, g = lane >> 4;

  for (int ti = 0; ti < 4; ++ti) {
    const int tile = blockIdx.x * 4 + ti;
    const int b = tile >> 8, i = tile & 255;
    const int bn = b * NN;
    const float mi = mask[bn + i];
    if (t < 256) Pis[t] = Pi[((size_t)(bn + i)) * HH + t];
    __syncthreads();

    const int m = wv * 16 + lr;                     // this lane's edge row j
    const float mf = mi * mask[bn + m];
    const float* erow = emb_edge + ((size_t)(bn + i) * NN + m) * DD;

    // bfrag: e row (masked, bf16), canonical k-slots. Kept for the residual.
    s16x8 bfrag[4];
#pragma unroll
    for (int kt = 0; kt < 4; ++kt) {
      const float4 g0 = *(const float4*)(erow + kt * 32 + 4 * g);
      const float4 g1 = *(const float4*)(erow + kt * 32 + 16 + 4 * g);
      s16x8 bf;
      bf[0] = (short)f2bf(g0.x * mf); bf[1] = (short)f2bf(g0.y * mf);
      bf[2] = (short)f2bf(g0.z * mf); bf[3] = (short)f2bf(g0.w * mf);
      bf[4] = (short)f2bf(g1.x * mf); bf[5] = (short)f2bf(g1.y * mf);
      bf[6] = (short)f2bf(g1.z * mf); bf[7] = (short)f2bf(g1.w * mf);
      bfrag[kt] = bf;
    }

    // GEMM1 (swapped): S[h][m]; epilogue folds Pi+Pj+relu into GEMM2 fragments
    const float* PjRow = Pj + ((size_t)(bn + m)) * HH;
    s16x8 a2f[8];
#pragma unroll
    for (int hf = 0; hf < 16; ++hf) {
      f32x4 acc = {0.f, 0.f, 0.f, 0.f};
      const short* wr = w1t + (hf * 16 + lr) * 128;
#pragma unroll
      for (int kt = 0; kt < 4; ++kt) {
        const s16x8 af = *(const s16x8*)(wr + SWZ(kt * 32 + 8 * g, lr));
        acc = __builtin_amdgcn_mfma_f32_16x16x32_bf16(af, bfrag[kt], acc, 0, 0, 0);
      }
      const float4 piv = *(const float4*)(Pis + hf * 16 + 4 * g);
      const float4 pjv = *(const float4*)(PjRow + hf * 16 + 4 * g);
      const int kt2 = hf >> 1, sl = (hf & 1) * 4;
      a2f[kt2][sl + 0] = (short)f2bf(fmaxf(acc[0] + piv.x + pjv.x, 0.f));
      a2f[kt2][sl + 1] = (short)f2bf(fmaxf(acc[1] + piv.y + pjv.y, 0.f));
      a2f[kt2][sl + 2] = (short)f2bf(fmaxf(acc[2] + piv.z + pjv.z, 0.f));
      a2f[kt2][sl + 3] = (short)f2bf(fmaxf(acc[3] + piv.w + pjv.w, 0.f));
    }

    // GEMM2 (swapped): D[dout][m] = W2^T-frag x act-frag. Lane's col = own row m.
    f32x4 acc2[8];
#pragma unroll
    for (int n2 = 0; n2 < 8; ++n2) { acc2[n2][0] = 0.f; acc2[n2][1] = 0.f; acc2[n2][2] = 0.f; acc2[n2][3] = 0.f; }
#pragma unroll
    for (int kt2 = 0; kt2 < 8; ++kt2) {
#pragma unroll
      for (int n2 = 0; n2 < 8; ++n2) {
        const s16x8 wf = *(const s16x8*)(w2t + (n2 * 16 + lr) * 256 + SWZ(kt2 * 32 + 8 * g, lr));
        acc2[n2] = __builtin_amdgcn_mfma_f32_16x16x32_bf16(wf, a2f[kt2], acc2[n2], 0, 0, 0);
      }
    }

    // Epilogue + LN, all within row m: lane holds douts n2*16+4g+jj.
    // Residual e comes from the lane's own bfrag (same (d mod 32) slot law).
    float sum = 0.f, sq = 0.f;
#pragma unroll
    for (int n2 = 0; n2 < 8; ++n2) {
      const int kt = n2 >> 1, sl = (n2 & 1) * 4;
#pragma unroll
      for (int jj = 0; jj < 4; ++jj) {
        const int dc = n2 * 16 + 4 * g + jj;
        const float x = acc2[n2][jj] + eb2s[dc] + bf2f((unsigned short)bfrag[kt][sl + jj]);
        acc2[n2][jj] = x;
        sum += x; sq += x * x;
      }
    }
    sum += __shfl_xor(sum, 16); sq += __shfl_xor(sq, 16);
    sum += __shfl_xor(sum, 32); sq += __shfl_xor(sq, 32);
    const float mu = sum * (1.f / 128.f);
    const float var = sq * (1.f / 128.f) - mu * mu;
    const float rstd = 1.f / sqrtf(var + 1e-5f);
    float* op = out_e + ((size_t)(bn + i) * NN + m) * DD;
#pragma unroll
    for (int n2 = 0; n2 < 8; ++n2) {
      const int dc0 = n2 * 16 + 4 * g;
      f32x4 o;
#pragma unroll
      for (int jj = 0; jj < 4; ++jj)
        o[jj] = (acc2[n2][jj] - mu) * rstd * gEs[dc0 + jj] + bEs[dc0 + jj];
      *(f32x4*)(op + dc0) = o;
    }
    __syncthreads();   // protect Pis before next tile's overwrite
  }
}

// ---------------------------------------------------------------------------
extern "C" void kernel_launch(void* const* d_in, const int* in_sizes, int n_in,
                              void* d_out, int out_size, void* d_ws, size_t ws_size,
                              hipStream_t stream) {
  (void)in_sizes; (void)n_in; (void)out_size;
  const float* emb_node = (const float*)d_in[0];
  const float* emb_edge = (const float*)d_in[1];
  const float* adj      = (const float*)d_in[2];
  const float* mask     = (const float*)d_in[3];
  const float* nW1 = (const float*)d_in[4];
  const float* nb1 = (const float*)d_in[5];
  const float* nW2 = (const float*)d_in[6];
  const float* nb2 = (const float*)d_in[7];
  const float* eW1 = (const float*)d_in[8];
  const float* eb1 = (const float*)d_in[9];
  const float* eW2 = (const float*)d_in[10];
  const float* eb2 = (const float*)d_in[11];
  const float* gX = (const float*)d_in[12];
  const float* bX = (const float*)d_in[13];
  const float* gE = (const float*)d_in[14];
  const float* bE = (const float*)d_in[15];

  float* out_x = (float*)d_out;                 // (4,256,128)
  float* out_e = out_x + (size_t)NB * NN * DD;  // (4,256,256,128)

  // Workspace: part[nch][1024][128] + Pi[1024][256] + Pj[1024][256]
  const size_t need8 = ((size_t)8 * NB * NN * DD + 2 * (size_t)NB * NN * HH) * 4;
  const int nch = (ws_size >= need8) ? 8 : 4;
  float* part = (float*)d_ws;
  float* Pi   = part + (size_t)nch * NB * NN * DD;
  float* Pj   = Pi + (size_t)NB * NN * HH;

  if (nch == 8)
    k_aggA<8><<<NB * 32 * 8, 256, 0, stream>>>(emb_node, emb_edge, adj, mask, part);
  else
    k_aggA<4><<<NB * 32 * 4, 256, 0, stream>>>(emb_node, emb_edge, adj, mask, part);
  k_node<<<NB * NN / 4, 256, 0, stream>>>(emb_node, mask, part, nch, nW1, nb1, nW2, nb2,
                                          eW1, eb1, gX, bX, out_x, Pi, Pj);
  k_edge<<<256, 1024, 0, stream>>>(emb_edge, mask, Pi, Pj, eW1, eW2, eb2, gE, bE, out_e);
}

// Round 7
// 421.710 us; speedup vs baseline: 1.1310x; 1.1310x over previous
//
#include <hip/hip_runtime.h>
#include <hip/hip_bf16.h>

#define NB 4
#define NN 256
#define DD 128
#define HH 256

typedef float f32x4 __attribute__((ext_vector_type(4)));
typedef short s16x8 __attribute__((ext_vector_type(8)));

static __device__ __forceinline__ unsigned short f2bf(float x) {
  unsigned int u = __builtin_bit_cast(unsigned int, x);
  u += 0x7fffu + ((u >> 16) & 1u);   // RNE
  return (unsigned short)(u >> 16);
}

static __device__ __forceinline__ float bf2f(unsigned short h) {
  unsigned int u = ((unsigned int)h) << 16;
  return __builtin_bit_cast(float, u);
}

// XOR-swizzle on short-offset within a row; 16B granules, bits 3..5
#define SWZ(off, row) ((off) ^ (((row) & 7) << 3))

// ---------------------------------------------------------------------------
// Kernel 1: agg partials, contiguous-stream layout.
// part[ic][b*256+j][d] = sum_{i in chunk} adj[b,i,j]*mi*(x[b,i,d]+e[b,i,j,d]*mj)
// ---------------------------------------------------------------------------
template<int NCH>
__global__ __launch_bounds__(256) void k_aggA(
    const float* __restrict__ emb_node, const float* __restrict__ emb_edge,
    const float* __restrict__ adj, const float* __restrict__ mask,
    float* __restrict__ part) {
  constexpr int IPC = NN / NCH;
  const int bid = blockIdx.x;
  const int b = bid / (32 * NCH);
  const int rem = bid % (32 * NCH);
  const int jc = rem / NCH, ic = rem % NCH;
  const int t = threadIdx.x;
  const int jl = t >> 5, dq = (t & 31) * 4;
  const int j = jc * 8 + jl;
  const int bj = b * NN + j;
  const float mj = mask[bj];
  f32x4 acc = {0.f, 0.f, 0.f, 0.f};
#pragma unroll 4
  for (int ii = 0; ii < IPC; ++ii) {
    const int bi = b * NN + ic * IPC + ii;
    const float am = adj[(size_t)bi * NN + j] * mask[bi];
    const float4 ev = *(const float4*)(emb_edge + ((size_t)bi * NN + j) * DD + dq);
    const float4 xv = *(const float4*)(emb_node + (size_t)bi * DD + dq);
    acc[0] += am * (xv.x + mj * ev.x);
    acc[1] += am * (xv.y + mj * ev.y);
    acc[2] += am * (xv.z + mj * ev.z);
    acc[3] += am * (xv.w + mj * ev.w);
  }
  *(f32x4*)(part + ((size_t)ic * (NB * NN) + bj) * DD + dq) = acc;
}

// ---------------------------------------------------------------------------
// Kernel 2: reduce partials -> x_new_pre; node MLP; out_x = LN(x + x_mlp);
//           Pi = x_mlp@W1a; Pj = x_mlp@W1b + eb1.  4 rows/block, 256 blocks.
// ---------------------------------------------------------------------------
__global__ __launch_bounds__(256) void k_node(
    const float* __restrict__ emb_node, const float* __restrict__ mask,
    const float* __restrict__ part, int nch,
    const float* __restrict__ nW1, const float* __restrict__ nb1,
    const float* __restrict__ nW2, const float* __restrict__ nb2,
    const float* __restrict__ eW1, const float* __restrict__ eb1,
    const float* __restrict__ gX, const float* __restrict__ bX,
    float* __restrict__ out_x, float* __restrict__ Pi, float* __restrict__ Pj) {
  __shared__ float xr[4][DD];
  __shared__ float hb[4][HH];
  __shared__ float xmb[4][DD];
  const int t = threadIdx.x;
  const int row0 = blockIdx.x * 4;
  for (int k = t; k < 4 * DD; k += 256) {
    const int row = row0 + (k >> 7), d = k & 127;
    float v = emb_node[(size_t)row * DD + d] * mask[row];
    for (int cc = 0; cc < nch; ++cc) v += part[((size_t)cc * (NB * NN) + row) * DD + d];
    xr[k >> 7][d] = v;
  }
  __syncthreads();
  { // layer 1
    float a0 = nb1[t], a1 = a0, a2 = a0, a3 = a0;
#pragma unroll 4
    for (int d = 0; d < DD; ++d) {
      float w = nW1[d * HH + t];
      a0 = fmaf(xr[0][d], w, a0); a1 = fmaf(xr[1][d], w, a1);
      a2 = fmaf(xr[2][d], w, a2); a3 = fmaf(xr[3][d], w, a3);
    }
    hb[0][t] = fmaxf(a0, 0.f); hb[1][t] = fmaxf(a1, 0.f);
    hb[2][t] = fmaxf(a2, 0.f); hb[3][t] = fmaxf(a3, 0.f);
  }
  __syncthreads();
  { // layer 2
    const int d = t & 127, rp = (t >> 7) * 2;
    float a0 = nb2[d], a1 = a0;
#pragma unroll 4
    for (int h = 0; h < HH; ++h) {
      float w = nW2[h * DD + d];
      a0 = fmaf(hb[rp][h], w, a0);
      a1 = fmaf(hb[rp + 1][h], w, a1);
    }
    xmb[rp][d] = a0; xmb[rp + 1][d] = a1;
  }
  __syncthreads();
  { // out_x = LN(x + x_mlp)
    const int w = t >> 6, l = t & 63;
    const int grow = row0 + w;
    const float m = mask[grow];
    const int d0 = 2 * l;
    float v0 = emb_node[(size_t)grow * DD + d0] * m + xmb[w][d0];
    float v1 = emb_node[(size_t)grow * DD + d0 + 1] * m + xmb[w][d0 + 1];
    float s = v0 + v1, s2 = v0 * v0 + v1 * v1;
#pragma unroll
    for (int off = 1; off < 64; off <<= 1) { s += __shfl_xor(s, off); s2 += __shfl_xor(s2, off); }
    const float mu = s * (1.f / 128.f);
    const float var = s2 * (1.f / 128.f) - mu * mu;
    const float rstd = 1.f / sqrtf(var + 1e-5f);
    out_x[(size_t)grow * DD + d0] = (v0 - mu) * rstd * gX[d0] + bX[d0];
    out_x[(size_t)grow * DD + d0 + 1] = (v1 - mu) * rstd * gX[d0 + 1] + bX[d0 + 1];
  }
  { // Pi / Pj
    float pi0 = 0.f, pi1 = 0.f, pi2 = 0.f, pi3 = 0.f;
    const float e1 = eb1[t];
    float pj0 = e1, pj1 = e1, pj2 = e1, pj3 = e1;
#pragma unroll 2
    for (int d = 0; d < DD; ++d) {
      const float wa = eW1[d * HH + t];
      const float wb = eW1[(DD + d) * HH + t];
      const float x0 = xmb[0][d], x1 = xmb[1][d], x2 = xmb[2][d], x3 = xmb[3][d];
      pi0 = fmaf(x0, wa, pi0); pi1 = fmaf(x1, wa, pi1);
      pi2 = fmaf(x2, wa, pi2); pi3 = fmaf(x3, wa, pi3);
      pj0 = fmaf(x0, wb, pj0); pj1 = fmaf(x1, wb, pj1);
      pj2 = fmaf(x2, wb, pj2); pj3 = fmaf(x3, wb, pj3);
    }
    Pi[(size_t)(row0 + 0) * HH + t] = pi0; Pi[(size_t)(row0 + 1) * HH + t] = pi1;
    Pi[(size_t)(row0 + 2) * HH + t] = pi2; Pi[(size_t)(row0 + 3) * HH + t] = pi3;
    Pj[(size_t)(row0 + 0) * HH + t] = pj0; Pj[(size_t)(row0 + 1) * HH + t] = pj1;
    Pj[(size_t)(row0 + 2) * HH + t] = pj2; Pj[(size_t)(row0 + 3) * HH + t] = pj3;
  }
}

// ---------------------------------------------------------------------------
// Kernel 3: edge MLP + residual LN, STREAMED hidden activation.
// r3/r4/r6 profiles proved hipcc pins 16-wave workgroups at 64 arch VGPRs
// (launch_bounds 2nd arg ignored) and the old structure (a2f[8] fully
// materialized, ~75+ live VGPRs) spilled ~250 MB/launch to scratch.
// New inner loop: per kt2 (h-block of 32), compute the two GEMM1 columns
// into AGPR acc, fold Pi+Pj+relu into ONE transient s16x8, immediately
// accumulate the 8 GEMM2 MFMAs (acc2 in AGPRs), discard.  Live arch state:
// bfrag 16 + 1 octet + addrs ~= 50 VGPRs -> fits the 64 cap, no spill.
// ---------------------------------------------------------------------------
__global__ __launch_bounds__(1024, 1) void k_edge(
    const float* __restrict__ emb_edge, const float* __restrict__ mask,
    const float* __restrict__ Pi, const float* __restrict__ Pj,
    const float* __restrict__ eW1, const float* __restrict__ eW2,
    const float* __restrict__ eb2, const float* __restrict__ gE,
    const float* __restrict__ bE, float* __restrict__ out_e) {
  __shared__ __align__(16) unsigned char smem[133632];
  short* w1t = (short*)smem;                 // [h=256][128 shorts]  = 65536 B
  short* w2t = (short*)(smem + 65536);       // [dout=128][256 shorts] = 65536 B
  float* Pis  = (float*)(smem + 131072);     // 256 f32
  float* eb2s = (float*)(smem + 132096);     // 128 f32
  float* gEs  = (float*)(smem + 132608);     // 128 f32
  float* bEs  = (float*)(smem + 133120);     // 128 f32

  const int t = threadIdx.x;
  // Stage W1c^T: slot p = kt*32 + 8g + s holds k = kt*32 + (s<4 ? 4g+s : 16+4g+s-4)
  for (int idx = t; idx < DD * HH; idx += 1024) {
    const int h = idx & 255, p = idx >> 8;          // p in [0,128)
    const int kt = p >> 5, r = p & 31, g = r >> 3, s = r & 7;
    const int k = kt * 32 + (s < 4 ? 4 * g + s : 16 + 4 * g + (s - 4));
    w1t[h * 128 + SWZ(p, h)] = (short)f2bf(eW1[(2 * DD + k) * HH + h]);
  }
  // Stage W2^T with same slot convention over h
  for (int idx = t; idx < DD * HH; idx += 1024) {
    const int dout = idx & 127, p = idx >> 7;       // p in [0,256)
    const int kt = p >> 5, r = p & 31, g = r >> 3, s = r & 7;
    const int h = kt * 32 + (s < 4 ? 4 * g + s : 16 + 4 * g + (s - 4));
    w2t[dout * 256 + SWZ(p, dout)] = (short)f2bf(eW2[h * DD + dout]);
  }
  if (t < 128) { eb2s[t] = eb2[t]; gEs[t] = gE[t]; bEs[t] = bE[t]; }
  __syncthreads();

  const int wv = t >> 6, lane = t & 63;
  const int lr = lane & 15, g = lane >> 4;

  for (int ti = 0; ti < 4; ++ti) {
    const int tile = blockIdx.x * 4 + ti;
    const int b = tile >> 8, i = tile & 255;
    const int bn = b * NN;
    const float mi = mask[bn + i];
    if (t < 256) Pis[t] = Pi[((size_t)(bn + i)) * HH + t];
    __syncthreads();

    const int m = wv * 16 + lr;                     // this lane's edge row j
    const float mf = mi * mask[bn + m];
    const float* erow = emb_edge + ((size_t)(bn + i) * NN + m) * DD;

    // bfrag: e row (masked, bf16), canonical k-slots. Kept for the residual.
    s16x8 bfrag[4];
#pragma unroll
    for (int kt = 0; kt < 4; ++kt) {
      const float4 g0 = *(const float4*)(erow + kt * 32 + 4 * g);
      const float4 g1 = *(const float4*)(erow + kt * 32 + 16 + 4 * g);
      s16x8 bf;
      bf[0] = (short)f2bf(g0.x * mf); bf[1] = (short)f2bf(g0.y * mf);
      bf[2] = (short)f2bf(g0.z * mf); bf[3] = (short)f2bf(g0.w * mf);
      bf[4] = (short)f2bf(g1.x * mf); bf[5] = (short)f2bf(g1.y * mf);
      bf[6] = (short)f2bf(g1.z * mf); bf[7] = (short)f2bf(g1.w * mf);
      bfrag[kt] = bf;
    }

    // Fused GEMM1->GEMM2, streamed per h-block of 32 (kt2).
    const float* PjRow = Pj + ((size_t)(bn + m)) * HH;
    f32x4 acc2[8];
#pragma unroll
    for (int n2 = 0; n2 < 8; ++n2) { acc2[n2][0] = 0.f; acc2[n2][1] = 0.f; acc2[n2][2] = 0.f; acc2[n2][3] = 0.f; }
#pragma unroll 2
    for (int kt2 = 0; kt2 < 8; ++kt2) {
      s16x8 a2f;
#pragma unroll
      for (int half = 0; half < 2; ++half) {
        const int hf = kt2 * 2 + half;
        f32x4 acc = {0.f, 0.f, 0.f, 0.f};
        const short* wr = w1t + (hf * 16 + lr) * 128;
#pragma unroll
        for (int kt = 0; kt < 4; ++kt) {
          const s16x8 af = *(const s16x8*)(wr + SWZ(kt * 32 + 8 * g, lr));
          acc = __builtin_amdgcn_mfma_f32_16x16x32_bf16(af, bfrag[kt], acc, 0, 0, 0);
        }
        const float4 piv = *(const float4*)(Pis + hf * 16 + 4 * g);
        const float4 pjv = *(const float4*)(PjRow + hf * 16 + 4 * g);
        const int sl = half * 4;
        a2f[sl + 0] = (short)f2bf(fmaxf(acc[0] + piv.x + pjv.x, 0.f));
        a2f[sl + 1] = (short)f2bf(fmaxf(acc[1] + piv.y + pjv.y, 0.f));
        a2f[sl + 2] = (short)f2bf(fmaxf(acc[2] + piv.z + pjv.z, 0.f));
        a2f[sl + 3] = (short)f2bf(fmaxf(acc[3] + piv.w + pjv.w, 0.f));
      }
#pragma unroll
      for (int n2 = 0; n2 < 8; ++n2) {
        const s16x8 wf = *(const s16x8*)(w2t + (n2 * 16 + lr) * 256 + SWZ(kt2 * 32 + 8 * g, lr));
        acc2[n2] = __builtin_amdgcn_mfma_f32_16x16x32_bf16(wf, a2f, acc2[n2], 0, 0, 0);
      }
    }

    // Epilogue + LN, all within row m: lane holds douts n2*16+4g+jj.
    // Residual e comes from the lane's own bfrag (same (d mod 32) slot law).
    float sum = 0.f, sq = 0.f;
#pragma unroll
    for (int n2 = 0; n2 < 8; ++n2) {
      const int kt = n2 >> 1, sl = (n2 & 1) * 4;
#pragma unroll
      for (int jj = 0; jj < 4; ++jj) {
        const int dc = n2 * 16 + 4 * g + jj;
        const float x = acc2[n2][jj] + eb2s[dc] + bf2f((unsigned short)bfrag[kt][sl + jj]);
        acc2[n2][jj] = x;
        sum += x; sq += x * x;
      }
    }
    sum += __shfl_xor(sum, 16); sq += __shfl_xor(sq, 16);
    sum += __shfl_xor(sum, 32); sq += __shfl_xor(sq, 32);
    const float mu = sum * (1.f / 128.f);
    const float var = sq * (1.f / 128.f) - mu * mu;
    const float rstd = 1.f / sqrtf(var + 1e-5f);
    float* op = out_e + ((size_t)(bn + i) * NN + m) * DD;
#pragma unroll
    for (int n2 = 0; n2 < 8; ++n2) {
      const int dc0 = n2 * 16 + 4 * g;
      f32x4 o;
#pragma unroll
      for (int jj = 0; jj < 4; ++jj)
        o[jj] = (acc2[n2][jj] - mu) * rstd * gEs[dc0 + jj] + bEs[dc0 + jj];
      *(f32x4*)(op + dc0) = o;
    }
    __syncthreads();   // protect Pis before next tile's overwrite
  }
}

// ---------------------------------------------------------------------------
extern "C" void kernel_launch(void* const* d_in, const int* in_sizes, int n_in,
                              void* d_out, int out_size, void* d_ws, size_t ws_size,
                              hipStream_t stream) {
  (void)in_sizes; (void)n_in; (void)out_size;
  const float* emb_node = (const float*)d_in[0];
  const float* emb_edge = (const float*)d_in[1];
  const float* adj      = (const float*)d_in[2];
  const float* mask     = (const float*)d_in[3];
  const float* nW1 = (const float*)d_in[4];
  const float* nb1 = (const float*)d_in[5];
  const float* nW2 = (const float*)d_in[6];
  const float* nb2 = (const float*)d_in[7];
  const float* eW1 = (const float*)d_in[8];
  const float* eb1 = (const float*)d_in[9];
  const float* eW2 = (const float*)d_in[10];
  const float* eb2 = (const float*)d_in[11];
  const float* gX = (const float*)d_in[12];
  const float* bX = (const float*)d_in[13];
  const float* gE = (const float*)d_in[14];
  const float* bE = (const float*)d_in[15];

  float* out_x = (float*)d_out;                 // (4,256,128)
  float* out_e = out_x + (size_t)NB * NN * DD;  // (4,256,256,128)

  // Workspace: part[nch][1024][128] + Pi[1024][256] + Pj[1024][256]
  const size_t need8 = ((size_t)8 * NB * NN * DD + 2 * (size_t)NB * NN * HH) * 4;
  const int nch = (ws_size >= need8) ? 8 : 4;
  float* part = (float*)d_ws;
  float* Pi   = part + (size_t)nch * NB * NN * DD;
  float* Pj   = Pi + (size_t)NB * NN * HH;

  if (nch == 8)
    k_aggA<8><<<NB * 32 * 8, 256, 0, stream>>>(emb_node, emb_edge, adj, mask, part);
  else
    k_aggA<4><<<NB * 32 * 4, 256, 0, stream>>>(emb_node, emb_edge, adj, mask, part);
  k_node<<<NB * NN / 4, 256, 0, stream>>>(emb_node, mask, part, nch, nW1, nb1, nW2, nb2,
                                          eW1, eb1, gX, bX, out_x, Pi, Pj);
  k_edge<<<256, 1024, 0, stream>>>(emb_edge, mask, Pi, Pj, eW1, eW2, eb2, gE, bE, out_e);
}